// Round 1
// baseline (761.344 us; speedup 1.0000x reference)
//
#include <hip/hip_runtime.h>
#include <hip/hip_bf16.h>
#include <math.h>

#define D_DIM 1024
#define F_DIM 4096
#define N_EXP 8

typedef __attribute__((ext_vector_type(4))) float f32x4;
typedef __attribute__((ext_vector_type(8))) short bf16x8;

__device__ __forceinline__ unsigned short f2bf(float f) {
    union { float f; unsigned int u; } v; v.f = f;
    unsigned int r = v.u + 0x7fffu + ((v.u >> 16) & 1u);  // RNE
    return (unsigned short)(r >> 16);
}

// async global->LDS, 16B per lane; LDS dest = lds_ptr(wave-uniform) + lane*16
#define GLDS16(g, l) __builtin_amdgcn_global_load_lds( \
    (const __attribute__((address_space(1))) void*)(g), \
    (__attribute__((address_space(3))) void*)(l), 16, 0, 0)

// depth-4 pipeline: 3 batches in flight while computing the oldest
#define WAIT12_BAR asm volatile("s_waitcnt vmcnt(12)\ns_barrier" ::: "memory")
#define WAIT9_BAR  asm volatile("s_waitcnt vmcnt(9)\ns_barrier" ::: "memory")
#define BAR        asm volatile("s_barrier" ::: "memory")
#define DRAIN      asm volatile("s_waitcnt vmcnt(0)" ::: "memory")

// ---------------- cast x fp32 -> bf16 ----------------
__global__ void cast_x_kernel(const float* __restrict__ x, unsigned short* __restrict__ xb, int n4) {
    int i = blockIdx.x * blockDim.x + threadIdx.x;
    if (i >= n4) return;
    float4 v = ((const float4*)x)[i];
    unsigned int lo = (unsigned int)f2bf(v.x) | ((unsigned int)f2bf(v.y) << 16);
    unsigned int hi = (unsigned int)f2bf(v.z) | ((unsigned int)f2bf(v.w) << 16);
    ((uint2*)xb)[i] = make_uint2(lo, hi);
}

// ---------------- transpose + cast: in [R][C] fp32 -> out [C][R] bf16 ----------------
// expert in low 3 bits of blockIdx.x -> transpose blocks of expert e land on XCD e
// (same mapping as the GEMMs), so freshly-cast weights are partially L2-local.
__global__ __launch_bounds__(256) void transpose_cast_kernel(
    const float* __restrict__ in, unsigned short* __restrict__ out, int R, int C) {
    __shared__ float tile[64][65];
    int e = blockIdx.x & 7;
    const float* inp = in + (size_t)e * R * C;
    unsigned short* outp = out + (size_t)e * R * C;
    int r0 = blockIdx.y * 64, c0 = (blockIdx.x >> 3) * 64;
    int tid = threadIdx.x;
    int tr = tid >> 4, tc = (tid & 15) * 4;
#pragma unroll
    for (int i = 0; i < 4; i++) {
        float4 v = *(const float4*)(inp + (size_t)(r0 + tr + i * 16) * C + c0 + tc);
        tile[tr + i * 16][tc + 0] = v.x;
        tile[tr + i * 16][tc + 1] = v.y;
        tile[tr + i * 16][tc + 2] = v.z;
        tile[tr + i * 16][tc + 3] = v.w;
    }
    __syncthreads();
    int wc = tid >> 4, wr = (tid & 15) * 4;
#pragma unroll
    for (int i = 0; i < 4; i++) {
        int c = wc + i * 16;
        ushort4 o;
        o.x = f2bf(tile[wr + 0][c]);
        o.y = f2bf(tile[wr + 1][c]);
        o.z = f2bf(tile[wr + 2][c]);
        o.w = f2bf(tile[wr + 3][c]);
        *(ushort4*)(outp + (size_t)(c0 + c) * R + r0 + wr) = o;
    }
}

// ---------------- gating: softmax top-2 + compaction + inverse map ----------------
__global__ void gate_kernel(const float* __restrict__ x, const float* __restrict__ gw,
                            int* __restrict__ counts, int* __restrict__ perm,
                            float* __restrict__ wts, int* __restrict__ islot, int T) {
    int wid = threadIdx.x >> 6, lane = threadIdx.x & 63;
    int token = blockIdx.x * 4 + wid;
    if (token >= T) return;
    float acc[N_EXP];
#pragma unroll
    for (int e = 0; e < N_EXP; e++) acc[e] = 0.f;
    const float* xr = x + (size_t)token * D_DIM;
    for (int i = 0; i < D_DIM / 64; i++) {
        int d = lane + 64 * i;
        float v = xr[d];
#pragma unroll
        for (int e = 0; e < N_EXP; e++) acc[e] += v * gw[d * N_EXP + e];
    }
#pragma unroll
    for (int off = 32; off >= 1; off >>= 1) {
#pragma unroll
        for (int e = 0; e < N_EXP; e++) acc[e] += __shfl_xor(acc[e], off, 64);
    }
    if (lane == 0) {
        float m = acc[0];
#pragma unroll
        for (int e = 1; e < N_EXP; e++) m = fmaxf(m, acc[e]);
        float p[N_EXP];
#pragma unroll
        for (int e = 0; e < N_EXP; e++) p[e] = expf(acc[e] - m);
        int a = 0;
        for (int e = 1; e < N_EXP; e++) if (p[e] > p[a]) a = e;
        int b = (a == 0) ? 1 : 0;
        for (int e = 0; e < N_EXP; e++) if (e != a && p[e] > p[b]) b = e;
        float s = p[a] + p[b];
        int pa = atomicAdd(&counts[a], 1);
        perm[(size_t)a * T + pa] = token; wts[(size_t)a * T + pa] = p[a] / s;
        int pb = atomicAdd(&counts[b], 1);
        perm[(size_t)b * T + pb] = token; wts[(size_t)b * T + pb] = p[b] / s;
        islot[2 * token + 0] = a * T + pa;
        islot[2 * token + 1] = b * T + pb;
    }
}

__global__ void offsets_kernel(const int* __restrict__ counts, int* __restrict__ offs) {
    if (threadIdx.x == 0 && blockIdx.x == 0) {
        int s = 0;
        for (int e = 0; e < N_EXP; e++) { offs[e] = s; s += counts[e]; }
        offs[N_EXP] = s;
    }
}

// ---------------- GEMM1: H = silu(Xe@W1t) * (Xe@W3t), 128x64 tile, depth-4 pipelined ----------------
__global__ __launch_bounds__(256, 4) void gemm1_kernel(
    const unsigned short* __restrict__ xb, const unsigned short* __restrict__ w1t,
    const unsigned short* __restrict__ w3t, const int* __restrict__ counts,
    const int* __restrict__ offs, const int* __restrict__ perm,
    unsigned short* __restrict__ hbuf, int T)
{
    // XCD swizzle: expert == low 3 bits == XCD -> one expert per XCD L2
    int bid = blockIdx.x;
    int s  = bid & 7;
    int rt = (bid >> 3) & 15;
    int ce = ((bid >> 7) << 3) | s;     // 0..511
    int e  = ce & 7;
    int ct = ce >> 3;                   // 0..63
    int n_e = counts[e];
    int row0 = rt * 128;
    if (row0 >= n_e) return;
    int c0 = ct * 64;
    const unsigned short* w1e = w1t + (size_t)e * F_DIM * D_DIM;
    const unsigned short* w3e = w3t + (size_t)e * F_DIM * D_DIM;
    __shared__ __attribute__((aligned(16))) unsigned short As[4][4096];
    __shared__ __attribute__((aligned(16))) unsigned short B1s[4][2048];
    __shared__ __attribute__((aligned(16))) unsigned short B3s[4][2048];
    int tid = threadIdx.x;
    int wid = tid >> 6, lane = tid & 63;
    int wm = wid >> 1, wn = wid & 1;
    int q = lane >> 4, ln = lane & 15;

    int sr = tid >> 2, sc = tid & 3;
    int q0 = sc ^ ((sr >> 1) & 3);
    int tok0 = perm[(size_t)e * T + min(row0 + sr, n_e - 1)];
    int tok1 = perm[(size_t)e * T + min(row0 + sr + 64, n_e - 1)];
    const unsigned short* ag0 = xb + (size_t)tok0 * D_DIM + q0 * 8;
    const unsigned short* ag1 = xb + (size_t)tok1 * D_DIM + q0 * 8;
    const unsigned short* b1g = w1e + (size_t)(c0 + sr) * D_DIM + q0 * 8;
    const unsigned short* b3g = w3e + (size_t)(c0 + sr) * D_DIM + q0 * 8;
    int wo = wid * 512;

    int a_off[4], b_off[2];
#pragma unroll
    for (int i = 0; i < 4; i++) {
        int m = wm * 64 + i * 16 + ln;
        a_off[i] = m * 32 + (q ^ ((m >> 1) & 3)) * 8;
    }
#pragma unroll
    for (int j = 0; j < 2; j++) {
        int n = wn * 32 + j * 16 + ln;
        b_off[j] = n * 32 + (q ^ ((n >> 1) & 3)) * 8;
    }

    f32x4 acc1[4][2], acc3[4][2];
#pragma unroll
    for (int i = 0; i < 4; i++)
#pragma unroll
        for (int j = 0; j < 2; j++) {
            acc1[i][j] = (f32x4){0.f, 0.f, 0.f, 0.f};
            acc3[i][j] = (f32x4){0.f, 0.f, 0.f, 0.f};
        }

#define ISSUE1(B, K) do { \
    GLDS16(ag0 + (K), &As[B][wo]); \
    GLDS16(ag1 + (K), &As[B][wo + 2048]); \
    GLDS16(b1g + (K), &B1s[B][wo]); \
    GLDS16(b3g + (K), &B3s[B][wo]); } while (0)

#define COMPUTE1(B) do { \
    bf16x8 af[4]; \
    _Pragma("unroll") for (int i = 0; i < 4; i++) af[i] = *(const bf16x8*)&As[B][a_off[i]]; \
    _Pragma("unroll") for (int j = 0; j < 2; j++) { \
        bf16x8 b1f = *(const bf16x8*)&B1s[B][b_off[j]]; \
        bf16x8 b3f = *(const bf16x8*)&B3s[B][b_off[j]]; \
        _Pragma("unroll") for (int i = 0; i < 4; i++) { \
            acc1[i][j] = __builtin_amdgcn_mfma_f32_16x16x32_bf16(af[i], b1f, acc1[i][j], 0, 0, 0); \
            acc3[i][j] = __builtin_amdgcn_mfma_f32_16x16x32_bf16(af[i], b3f, acc3[i][j], 0, 0, 0); \
        } \
    } } while (0)

    // prologue: 3 batches in flight
    ISSUE1(0, 0);
    ISSUE1(1, 32);
    ISSUE1(2, 64);
    for (int it = 0; it < 32; it += 4) {
        int k3 = it + 3, k4 = it + 4, k5 = it + 5, k6 = it + 6;
        ISSUE1(3, (k3 < 32) ? k3 * 32 : 0);   // redundant tail issues keep vmcnt accounting uniform
        WAIT12_BAR; COMPUTE1(0); BAR;
        ISSUE1(0, (k4 < 32) ? k4 * 32 : 0);
        WAIT12_BAR; COMPUTE1(1); BAR;
        ISSUE1(1, (k5 < 32) ? k5 * 32 : 0);
        WAIT12_BAR; COMPUTE1(2); BAR;
        ISSUE1(2, (k6 < 32) ? k6 * 32 : 0);
        WAIT12_BAR; COMPUTE1(3); BAR;
    }
    DRAIN;  // don't endpgm with LDS-DMA in flight

    int hb = offs[e];
#pragma unroll
    for (int i = 0; i < 4; i++) {
#pragma unroll
        for (int r = 0; r < 4; r++) {
            int grow = row0 + wm * 64 + i * 16 + q * 4 + r;
            if (grow < n_e) {
                size_t hrow = (size_t)(hb + grow) * F_DIM;
#pragma unroll
                for (int j = 0; j < 2; j++) {
                    int col = c0 + wn * 32 + j * 16 + ln;
                    float p1 = acc1[i][j][r];
                    float p3 = acc3[i][j][r];
                    float h = (p1 / (1.f + expf(-p1))) * p3;
                    hbuf[hrow + col] = f2bf(h);
                }
            }
        }
    }
}

// ---------------- GEMM2: obuf[slot] = (He @ W2t) * w, 128x64 tile, depth-4 pipelined ----------------
__global__ __launch_bounds__(256, 4) void gemm2_kernel(
    const unsigned short* __restrict__ hbuf, const unsigned short* __restrict__ w2t,
    const int* __restrict__ counts, const int* __restrict__ offs,
    const float* __restrict__ wts, float* __restrict__ obuf, int T)
{
    int bid = blockIdx.x;
    int s  = bid & 7;
    int rt = (bid >> 3) & 15;
    int ce = ((bid >> 7) << 3) | s;     // 0..127
    int e  = ce & 7;
    int ct = ce >> 3;                   // 0..15
    int n_e = counts[e];
    int row0 = rt * 128;
    if (row0 >= n_e) return;
    int c0 = ct * 64;
    const unsigned short* w2e = w2t + (size_t)e * D_DIM * F_DIM;  // [D][F] bf16
    __shared__ __attribute__((aligned(16))) unsigned short As[4][4096];
    __shared__ __attribute__((aligned(16))) unsigned short Bs[4][2048];
    int tid = threadIdx.x;
    int wid = tid >> 6, lane = tid & 63;
    int wm = wid >> 1, wn = wid & 1;
    int q = lane >> 4, ln = lane & 15;
    int hb = offs[e];

    int sr = tid >> 2, sc = tid & 3;
    int q0 = sc ^ ((sr >> 1) & 3);
    int ar0 = hb + min(row0 + sr, n_e - 1);
    int ar1 = hb + min(row0 + sr + 64, n_e - 1);
    const unsigned short* ag0 = hbuf + (size_t)ar0 * F_DIM + q0 * 8;
    const unsigned short* ag1 = hbuf + (size_t)ar1 * F_DIM + q0 * 8;
    const unsigned short* bg  = w2e + (size_t)(c0 + sr) * F_DIM + q0 * 8;
    int wo = wid * 512;

    int a_off[4], b_off[2];
#pragma unroll
    for (int i = 0; i < 4; i++) {
        int m = wm * 64 + i * 16 + ln;
        a_off[i] = m * 32 + (q ^ ((m >> 1) & 3)) * 8;
    }
#pragma unroll
    for (int j = 0; j < 2; j++) {
        int n = wn * 32 + j * 16 + ln;
        b_off[j] = n * 32 + (q ^ ((n >> 1) & 3)) * 8;
    }

    f32x4 acc[4][2];
#pragma unroll
    for (int i = 0; i < 4; i++)
#pragma unroll
        for (int j = 0; j < 2; j++) acc[i][j] = (f32x4){0.f, 0.f, 0.f, 0.f};

#define ISSUE2(B, K) do { \
    GLDS16(ag0 + (K), &As[B][wo]); \
    GLDS16(ag1 + (K), &As[B][wo + 2048]); \
    GLDS16(bg + (K), &Bs[B][wo]); } while (0)

#define COMPUTE2(B) do { \
    bf16x8 af[4]; \
    _Pragma("unroll") for (int i = 0; i < 4; i++) af[i] = *(const bf16x8*)&As[B][a_off[i]]; \
    _Pragma("unroll") for (int j = 0; j < 2; j++) { \
        bf16x8 bf = *(const bf16x8*)&Bs[B][b_off[j]]; \
        _Pragma("unroll") for (int i = 0; i < 4; i++) \
            acc[i][j] = __builtin_amdgcn_mfma_f32_16x16x32_bf16(af[i], bf, acc[i][j], 0, 0, 0); \
    } } while (0)

    ISSUE2(0, 0);
    ISSUE2(1, 32);
    ISSUE2(2, 64);
    for (int it = 0; it < 128; it += 4) {
        int k3 = it + 3, k4 = it + 4, k5 = it + 5, k6 = it + 6;
        ISSUE2(3, (k3 < 128) ? k3 * 32 : 0);
        WAIT9_BAR; COMPUTE2(0); BAR;
        ISSUE2(0, (k4 < 128) ? k4 * 32 : 0);
        WAIT9_BAR; COMPUTE2(1); BAR;
        ISSUE2(1, (k5 < 128) ? k5 * 32 : 0);
        WAIT9_BAR; COMPUTE2(2); BAR;
        ISSUE2(2, (k6 < 128) ? k6 * 32 : 0);
        WAIT9_BAR; COMPUTE2(3); BAR;
    }
    DRAIN;

#pragma unroll
    for (int i = 0; i < 4; i++) {
#pragma unroll
        for (int r = 0; r < 4; r++) {
            int grow = row0 + wm * 64 + i * 16 + q * 4 + r;
            if (grow < n_e) {
                float w = wts[(size_t)e * T + grow];
                float* orow = obuf + (size_t)(hb + grow) * D_DIM;
#pragma unroll
                for (int j = 0; j < 2; j++) {
                    int col = c0 + wn * 32 + j * 16 + ln;
                    orow[col] = acc[i][j][r] * w;
                }
            }
        }
    }
}

// ---------------- combine: out[t] = obuf[slot0(t)] + obuf[slot1(t)] ----------------
__global__ void combine_kernel(const float* __restrict__ obuf, const int* __restrict__ islot,
                               const int* __restrict__ offs, float* __restrict__ out, int T) {
    int idx = blockIdx.x * 256 + threadIdx.x;   // one float4 each
    int n4 = T * (D_DIM / 4);
    if (idx >= n4) return;
    int t = idx / (D_DIM / 4);
    int c4 = idx - t * (D_DIM / 4);
    int v0 = islot[2 * t], v1 = islot[2 * t + 1];
    int e0 = v0 / T, e1 = v1 / T;
    int s0 = offs[e0] + (v0 - e0 * T);
    int s1 = offs[e1] + (v1 - e1 * T);
    float4 a = ((const float4*)obuf)[(size_t)s0 * (D_DIM / 4) + c4];
    float4 b = ((const float4*)obuf)[(size_t)s1 * (D_DIM / 4) + c4];
    float4 o; o.x = a.x + b.x; o.y = a.y + b.y; o.z = a.z + b.z; o.w = a.w + b.w;
    ((float4*)out)[idx] = o;
}

extern "C" void kernel_launch(void* const* d_in, const int* in_sizes, int n_in,
                              void* d_out, int out_size, void* d_ws, size_t ws_size,
                              hipStream_t stream) {
    const float* x  = (const float*)d_in[0];
    const float* gw = (const float*)d_in[1];
    const float* w1 = (const float*)d_in[2];
    const float* w2 = (const float*)d_in[3];
    const float* w3 = (const float*)d_in[4];
    float* out = (float*)d_out;
    int T = in_sizes[0] / D_DIM;   // 2048

    char* ws = (char*)d_ws;
    size_t off = 0;
    unsigned short* xb = (unsigned short*)(ws + off); off += (size_t)T * D_DIM * 2;
    int* counts = (int*)(ws + off); off += 256;
    int* offs   = (int*)(ws + off); off += 256;
    int* perm   = (int*)(ws + off); off += (size_t)N_EXP * T * 4;
    float* wts  = (float*)(ws + off); off += (size_t)N_EXP * T * 4;
    int* islot  = (int*)(ws + off); off += (size_t)2 * T * 4;
    unsigned short* hbuf = (unsigned short*)(ws + off); off += (size_t)2 * T * F_DIM * 2;
    unsigned short* w1t  = (unsigned short*)(ws + off); off += (size_t)N_EXP * D_DIM * F_DIM * 2;
    unsigned short* w3t  = (unsigned short*)(ws + off); off += (size_t)N_EXP * D_DIM * F_DIM * 2;
    unsigned short* w2t  = w1t;            // aliased: w1t dead after gemm1
    float* obuf = (float*)w3t;             // aliased: w3t dead after gemm1 (16 MB < 64 MB)

    hipMemsetAsync(counts, 0, 256, stream);

    int n4 = T * D_DIM / 4;
    cast_x_kernel<<<(n4 + 255) / 256, 256, 0, stream>>>(x, xb, n4);
    gate_kernel<<<T / 4, 256, 0, stream>>>(x, gw, counts, perm, wts, islot, T);
    offsets_kernel<<<1, 64, 0, stream>>>(counts, offs);

    // expert in low 3 bits of grid.x -> XCD-aligned with the GEMMs
    dim3 gt13((F_DIM / 64) * N_EXP, D_DIM / 64);
    transpose_cast_kernel<<<gt13, 256, 0, stream>>>(w1, w1t, D_DIM, F_DIM);
    transpose_cast_kernel<<<gt13, 256, 0, stream>>>(w3, w3t, D_DIM, F_DIM);

    gemm1_kernel<<<(F_DIM / 64) * N_EXP * 16, 256, 0, stream>>>(
        xb, w1t, w3t, counts, offs, perm, hbuf, T);

    dim3 gt2((D_DIM / 64) * N_EXP, F_DIM / 64);
    transpose_cast_kernel<<<gt2, 256, 0, stream>>>(w2, w2t, F_DIM, D_DIM);

    gemm2_kernel<<<(D_DIM / 64) * N_EXP * 16, 256, 0, stream>>>(
        hbuf, w2t, counts, offs, wts, obuf, T);

    combine_kernel<<<(T * D_DIM / 4 + 255) / 256, 256, 0, stream>>>(obuf, islot, offs, out, T);
}

// Round 2
// 721.393 us; speedup vs baseline: 1.0554x; 1.0554x over previous
//
#include <hip/hip_runtime.h>
#include <hip/hip_bf16.h>
#include <math.h>

#define D_DIM 1024
#define F_DIM 4096
#define N_EXP 8

typedef __attribute__((ext_vector_type(4))) float f32x4;
typedef __attribute__((ext_vector_type(8))) short bf16x8;

__device__ __forceinline__ unsigned short f2bf(float f) {
    union { float f; unsigned int u; } v; v.f = f;
    unsigned int r = v.u + 0x7fffu + ((v.u >> 16) & 1u);  // RNE
    return (unsigned short)(r >> 16);
}

// async global->LDS, 16B per lane; LDS dest = lds_ptr(wave-uniform) + lane*16
#define GLDS16(g, l) __builtin_amdgcn_global_load_lds( \
    (const __attribute__((address_space(1))) void*)(g), \
    (__attribute__((address_space(3))) void*)(l), 16, 0, 0)

// depth-2 pipeline, counted waits: wait for the current buffer's batch only
#define WAIT6_BAR asm volatile("s_waitcnt vmcnt(6)\ns_barrier" ::: "memory")
#define WAIT4_BAR asm volatile("s_waitcnt vmcnt(4)\ns_barrier" ::: "memory")
#define BAR       asm volatile("s_barrier" ::: "memory")
#define DRAIN     asm volatile("s_waitcnt vmcnt(0)" ::: "memory")

// ---------------- cast x fp32 -> bf16 ----------------
__global__ void cast_x_kernel(const float* __restrict__ x, unsigned short* __restrict__ xb, int n4) {
    int i = blockIdx.x * blockDim.x + threadIdx.x;
    if (i >= n4) return;
    float4 v = ((const float4*)x)[i];
    unsigned int lo = (unsigned int)f2bf(v.x) | ((unsigned int)f2bf(v.y) << 16);
    unsigned int hi = (unsigned int)f2bf(v.z) | ((unsigned int)f2bf(v.w) << 16);
    ((uint2*)xb)[i] = make_uint2(lo, hi);
}

// ---------------- transpose + cast: in [R][C] fp32 -> out [C][R] bf16 ----------------
// expert in low 3 bits of blockIdx.x -> transpose blocks of expert e land on XCD e
__global__ __launch_bounds__(256) void transpose_cast_kernel(
    const float* __restrict__ in, unsigned short* __restrict__ out, int R, int C) {
    __shared__ float tile[64][65];
    int e = blockIdx.x & 7;
    const float* inp = in + (size_t)e * R * C;
    unsigned short* outp = out + (size_t)e * R * C;
    int r0 = blockIdx.y * 64, c0 = (blockIdx.x >> 3) * 64;
    int tid = threadIdx.x;
    int tr = tid >> 4, tc = (tid & 15) * 4;
#pragma unroll
    for (int i = 0; i < 4; i++) {
        float4 v = *(const float4*)(inp + (size_t)(r0 + tr + i * 16) * C + c0 + tc);
        tile[tr + i * 16][tc + 0] = v.x;
        tile[tr + i * 16][tc + 1] = v.y;
        tile[tr + i * 16][tc + 2] = v.z;
        tile[tr + i * 16][tc + 3] = v.w;
    }
    __syncthreads();
    int wc = tid >> 4, wr = (tid & 15) * 4;
#pragma unroll
    for (int i = 0; i < 4; i++) {
        int c = wc + i * 16;
        ushort4 o;
        o.x = f2bf(tile[wr + 0][c]);
        o.y = f2bf(tile[wr + 1][c]);
        o.z = f2bf(tile[wr + 2][c]);
        o.w = f2bf(tile[wr + 3][c]);
        *(ushort4*)(outp + (size_t)(c0 + c) * R + r0 + wr) = o;
    }
}

// ---------------- gating: softmax top-2 + compaction + inverse map ----------------
__global__ void gate_kernel(const float* __restrict__ x, const float* __restrict__ gw,
                            int* __restrict__ counts, int* __restrict__ perm,
                            float* __restrict__ wts, int* __restrict__ islot, int T) {
    int wid = threadIdx.x >> 6, lane = threadIdx.x & 63;
    int token = blockIdx.x * 4 + wid;
    if (token >= T) return;
    float acc[N_EXP];
#pragma unroll
    for (int e = 0; e < N_EXP; e++) acc[e] = 0.f;
    const float* xr = x + (size_t)token * D_DIM;
    for (int i = 0; i < D_DIM / 64; i++) {
        int d = lane + 64 * i;
        float v = xr[d];
#pragma unroll
        for (int e = 0; e < N_EXP; e++) acc[e] += v * gw[d * N_EXP + e];
    }
#pragma unroll
    for (int off = 32; off >= 1; off >>= 1) {
#pragma unroll
        for (int e = 0; e < N_EXP; e++) acc[e] += __shfl_xor(acc[e], off, 64);
    }
    if (lane == 0) {
        float m = acc[0];
#pragma unroll
        for (int e = 1; e < N_EXP; e++) m = fmaxf(m, acc[e]);
        float p[N_EXP];
#pragma unroll
        for (int e = 0; e < N_EXP; e++) p[e] = expf(acc[e] - m);
        int a = 0;
        for (int e = 1; e < N_EXP; e++) if (p[e] > p[a]) a = e;
        int b = (a == 0) ? 1 : 0;
        for (int e = 0; e < N_EXP; e++) if (e != a && p[e] > p[b]) b = e;
        float s = p[a] + p[b];
        int pa = atomicAdd(&counts[a], 1);
        perm[(size_t)a * T + pa] = token; wts[(size_t)a * T + pa] = p[a] / s;
        int pb = atomicAdd(&counts[b], 1);
        perm[(size_t)b * T + pb] = token; wts[(size_t)b * T + pb] = p[b] / s;
        islot[2 * token + 0] = a * T + pa;
        islot[2 * token + 1] = b * T + pb;
    }
}

__global__ void offsets_kernel(const int* __restrict__ counts, int* __restrict__ offs) {
    if (threadIdx.x == 0 && blockIdx.x == 0) {
        int s = 0;
        for (int e = 0; e < N_EXP; e++) { offs[e] = s; s += counts[e]; }
        offs[N_EXP] = s;
    }
}

// ---------------- GEMM1: H = silu(Xe@W1t) * (Xe@W3t), 128x128 tile, depth-2 ----------------
__global__ __launch_bounds__(256, 2) void gemm1_kernel(
    const unsigned short* __restrict__ xb, const unsigned short* __restrict__ w1t,
    const unsigned short* __restrict__ w3t, const int* __restrict__ counts,
    const int* __restrict__ offs, const int* __restrict__ perm,
    unsigned short* __restrict__ hbuf, int T)
{
    // XCD swizzle: expert == low 3 bits == XCD -> one expert per XCD L2
    int bid = blockIdx.x;
    int s  = bid & 7;
    int rt = (bid >> 3) & 15;
    int ce = ((bid >> 7) << 3) | s;     // 0..255
    int e  = ce & 7;
    int ct = ce >> 3;                   // 0..31
    int n_e = counts[e];
    int row0 = rt * 128;
    if (row0 >= n_e) return;
    int c0 = ct * 128;
    const unsigned short* w1e = w1t + (size_t)e * F_DIM * D_DIM;
    const unsigned short* w3e = w3t + (size_t)e * F_DIM * D_DIM;
    __shared__ __attribute__((aligned(16))) unsigned short As[2][4096];
    __shared__ __attribute__((aligned(16))) unsigned short B1s[2][4096];
    __shared__ __attribute__((aligned(16))) unsigned short B3s[2][4096];
    int tid = threadIdx.x;
    int wid = tid >> 6, lane = tid & 63;
    int wm = wid >> 1, wn = wid & 1;
    int q = lane >> 4, ln = lane & 15;

    int sr = tid >> 2, sc = tid & 3;
    int q0 = sc ^ ((sr >> 1) & 3);
    int tok0 = perm[(size_t)e * T + min(row0 + sr, n_e - 1)];
    int tok1 = perm[(size_t)e * T + min(row0 + sr + 64, n_e - 1)];
    const unsigned short* ag0 = xb + (size_t)tok0 * D_DIM + q0 * 8;
    const unsigned short* ag1 = xb + (size_t)tok1 * D_DIM + q0 * 8;
    const unsigned short* b1g0 = w1e + (size_t)(c0 + sr) * D_DIM + q0 * 8;
    const unsigned short* b1g1 = w1e + (size_t)(c0 + sr + 64) * D_DIM + q0 * 8;
    const unsigned short* b3g0 = w3e + (size_t)(c0 + sr) * D_DIM + q0 * 8;
    const unsigned short* b3g1 = w3e + (size_t)(c0 + sr + 64) * D_DIM + q0 * 8;
    int wo = wid * 512;

    int a_off[4], b_off[4];
#pragma unroll
    for (int i = 0; i < 4; i++) {
        int m = wm * 64 + i * 16 + ln;
        a_off[i] = m * 32 + (q ^ ((m >> 1) & 3)) * 8;
    }
#pragma unroll
    for (int j = 0; j < 4; j++) {
        int n = wn * 64 + j * 16 + ln;
        b_off[j] = n * 32 + (q ^ ((n >> 1) & 3)) * 8;
    }

    f32x4 acc1[4][4], acc3[4][4];
#pragma unroll
    for (int i = 0; i < 4; i++)
#pragma unroll
        for (int j = 0; j < 4; j++) {
            acc1[i][j] = (f32x4){0.f, 0.f, 0.f, 0.f};
            acc3[i][j] = (f32x4){0.f, 0.f, 0.f, 0.f};
        }

#define ISSUE1(B, K) do { \
    GLDS16(ag0 + (K), &As[B][wo]); \
    GLDS16(ag1 + (K), &As[B][wo + 2048]); \
    GLDS16(b1g0 + (K), &B1s[B][wo]); \
    GLDS16(b1g1 + (K), &B1s[B][wo + 2048]); \
    GLDS16(b3g0 + (K), &B3s[B][wo]); \
    GLDS16(b3g1 + (K), &B3s[B][wo + 2048]); } while (0)

#define COMPUTE1(B) do { \
    bf16x8 af[4]; \
    _Pragma("unroll") for (int i = 0; i < 4; i++) af[i] = *(const bf16x8*)&As[B][a_off[i]]; \
    _Pragma("unroll") for (int j = 0; j < 4; j++) { \
        bf16x8 b1f = *(const bf16x8*)&B1s[B][b_off[j]]; \
        bf16x8 b3f = *(const bf16x8*)&B3s[B][b_off[j]]; \
        _Pragma("unroll") for (int i = 0; i < 4; i++) { \
            acc1[i][j] = __builtin_amdgcn_mfma_f32_16x16x32_bf16(af[i], b1f, acc1[i][j], 0, 0, 0); \
            acc3[i][j] = __builtin_amdgcn_mfma_f32_16x16x32_bf16(af[i], b3f, acc3[i][j], 0, 0, 0); \
        } \
    } } while (0)

    ISSUE1(0, 0);
    for (int it = 0; it < 32; it += 2) {
        int kn1 = (it + 1) * 32;
        ISSUE1(1, kn1);
        WAIT6_BAR;
        COMPUTE1(0);
        BAR;
        int kn2 = (it + 2 < 32) ? (it + 2) * 32 : 0;  // final issue redundant (never read)
        ISSUE1(0, kn2);
        WAIT6_BAR;
        COMPUTE1(1);
        BAR;
    }
    DRAIN;  // don't endpgm with LDS-DMA in flight

    int hb = offs[e];
#pragma unroll
    for (int i = 0; i < 4; i++) {
#pragma unroll
        for (int r = 0; r < 4; r++) {
            int grow = row0 + wm * 64 + i * 16 + q * 4 + r;
            if (grow < n_e) {
                size_t hrow = (size_t)(hb + grow) * F_DIM;
#pragma unroll
                for (int j = 0; j < 4; j++) {
                    int col = c0 + wn * 64 + j * 16 + ln;
                    float p1 = acc1[i][j][r];
                    float p3 = acc3[i][j][r];
                    float h = (p1 / (1.f + expf(-p1))) * p3;
                    hbuf[hrow + col] = f2bf(h);
                }
            }
        }
    }
}

// ---------------- GEMM2: obuf[slot] = (He @ W2t) * w, 128x128 tile, depth-2 ----------------
__global__ __launch_bounds__(256, 2) void gemm2_kernel(
    const unsigned short* __restrict__ hbuf, const unsigned short* __restrict__ w2t,
    const int* __restrict__ counts, const int* __restrict__ offs,
    const float* __restrict__ wts, float* __restrict__ obuf, int T)
{
    int bid = blockIdx.x;
    int s  = bid & 7;
    int rt = (bid >> 3) & 15;
    int ce = ((bid >> 7) << 3) | s;     // 0..63
    int e  = ce & 7;
    int ct = ce >> 3;                   // 0..7
    int n_e = counts[e];
    int row0 = rt * 128;
    if (row0 >= n_e) return;
    int c0 = ct * 128;
    const unsigned short* w2e = w2t + (size_t)e * D_DIM * F_DIM;  // [D][F] bf16
    __shared__ __attribute__((aligned(16))) unsigned short As[2][4096];
    __shared__ __attribute__((aligned(16))) unsigned short Bs[2][4096];
    int tid = threadIdx.x;
    int wid = tid >> 6, lane = tid & 63;
    int wm = wid >> 1, wn = wid & 1;
    int q = lane >> 4, ln = lane & 15;
    int hb = offs[e];

    int sr = tid >> 2, sc = tid & 3;
    int q0 = sc ^ ((sr >> 1) & 3);
    int ar0 = hb + min(row0 + sr, n_e - 1);
    int ar1 = hb + min(row0 + sr + 64, n_e - 1);
    const unsigned short* ag0 = hbuf + (size_t)ar0 * F_DIM + q0 * 8;
    const unsigned short* ag1 = hbuf + (size_t)ar1 * F_DIM + q0 * 8;
    const unsigned short* bg0 = w2e + (size_t)(c0 + sr) * F_DIM + q0 * 8;
    const unsigned short* bg1 = w2e + (size_t)(c0 + sr + 64) * F_DIM + q0 * 8;
    int wo = wid * 512;

    int a_off[4], b_off[4];
#pragma unroll
    for (int i = 0; i < 4; i++) {
        int m = wm * 64 + i * 16 + ln;
        a_off[i] = m * 32 + (q ^ ((m >> 1) & 3)) * 8;
    }
#pragma unroll
    for (int j = 0; j < 4; j++) {
        int n = wn * 64 + j * 16 + ln;
        b_off[j] = n * 32 + (q ^ ((n >> 1) & 3)) * 8;
    }

    f32x4 acc[4][4];
#pragma unroll
    for (int i = 0; i < 4; i++)
#pragma unroll
        for (int j = 0; j < 4; j++) acc[i][j] = (f32x4){0.f, 0.f, 0.f, 0.f};

#define ISSUE2(B, K) do { \
    GLDS16(ag0 + (K), &As[B][wo]); \
    GLDS16(ag1 + (K), &As[B][wo + 2048]); \
    GLDS16(bg0 + (K), &Bs[B][wo]); \
    GLDS16(bg1 + (K), &Bs[B][wo + 2048]); } while (0)

#define COMPUTE2(B) do { \
    bf16x8 af[4]; \
    _Pragma("unroll") for (int i = 0; i < 4; i++) af[i] = *(const bf16x8*)&As[B][a_off[i]]; \
    _Pragma("unroll") for (int j = 0; j < 4; j++) { \
        bf16x8 bf = *(const bf16x8*)&Bs[B][b_off[j]]; \
        _Pragma("unroll") for (int i = 0; i < 4; i++) \
            acc[i][j] = __builtin_amdgcn_mfma_f32_16x16x32_bf16(af[i], bf, acc[i][j], 0, 0, 0); \
    } } while (0)

    ISSUE2(0, 0);
    for (int it = 0; it < 128; it += 2) {
        int kn1 = (it + 1) * 32;
        ISSUE2(1, kn1);
        WAIT4_BAR;
        COMPUTE2(0);
        BAR;
        int kn2 = (it + 2 < 128) ? (it + 2) * 32 : 0;
        ISSUE2(0, kn2);
        WAIT4_BAR;
        COMPUTE2(1);
        BAR;
    }
    DRAIN;

#pragma unroll
    for (int i = 0; i < 4; i++) {
#pragma unroll
        for (int r = 0; r < 4; r++) {
            int grow = row0 + wm * 64 + i * 16 + q * 4 + r;
            if (grow < n_e) {
                float w = wts[(size_t)e * T + grow];
                float* orow = obuf + (size_t)(hb + grow) * D_DIM;
#pragma unroll
                for (int j = 0; j < 4; j++) {
                    int col = c0 + wn * 64 + j * 16 + ln;
                    orow[col] = acc[i][j][r] * w;
                }
            }
        }
    }
}

// ---------------- combine: out[t] = obuf[slot0(t)] + obuf[slot1(t)] ----------------
__global__ void combine_kernel(const float* __restrict__ obuf, const int* __restrict__ islot,
                               const int* __restrict__ offs, float* __restrict__ out, int T) {
    int idx = blockIdx.x * 256 + threadIdx.x;   // one float4 each
    int n4 = T * (D_DIM / 4);
    if (idx >= n4) return;
    int t = idx / (D_DIM / 4);
    int c4 = idx - t * (D_DIM / 4);
    int v0 = islot[2 * t], v1 = islot[2 * t + 1];
    int e0 = v0 / T, e1 = v1 / T;
    int s0 = offs[e0] + (v0 - e0 * T);
    int s1 = offs[e1] + (v1 - e1 * T);
    float4 a = ((const float4*)obuf)[(size_t)s0 * (D_DIM / 4) + c4];
    float4 b = ((const float4*)obuf)[(size_t)s1 * (D_DIM / 4) + c4];
    float4 o; o.x = a.x + b.x; o.y = a.y + b.y; o.z = a.z + b.z; o.w = a.w + b.w;
    ((float4*)out)[idx] = o;
}

extern "C" void kernel_launch(void* const* d_in, const int* in_sizes, int n_in,
                              void* d_out, int out_size, void* d_ws, size_t ws_size,
                              hipStream_t stream) {
    const float* x  = (const float*)d_in[0];
    const float* gw = (const float*)d_in[1];
    const float* w1 = (const float*)d_in[2];
    const float* w2 = (const float*)d_in[3];
    const float* w3 = (const float*)d_in[4];
    float* out = (float*)d_out;
    int T = in_sizes[0] / D_DIM;   // 2048

    char* ws = (char*)d_ws;
    size_t off = 0;
    unsigned short* xb = (unsigned short*)(ws + off); off += (size_t)T * D_DIM * 2;
    int* counts = (int*)(ws + off); off += 256;
    int* offs   = (int*)(ws + off); off += 256;
    int* perm   = (int*)(ws + off); off += (size_t)N_EXP * T * 4;
    float* wts  = (float*)(ws + off); off += (size_t)N_EXP * T * 4;
    int* islot  = (int*)(ws + off); off += (size_t)2 * T * 4;
    unsigned short* hbuf = (unsigned short*)(ws + off); off += (size_t)2 * T * F_DIM * 2;
    unsigned short* w1t  = (unsigned short*)(ws + off); off += (size_t)N_EXP * D_DIM * F_DIM * 2;
    unsigned short* w3t  = (unsigned short*)(ws + off); off += (size_t)N_EXP * D_DIM * F_DIM * 2;
    unsigned short* w2t  = w1t;            // aliased: w1t dead after gemm1
    float* obuf = (float*)w3t;             // aliased: w3t dead after gemm1 (16 MB < 64 MB)

    hipMemsetAsync(counts, 0, 256, stream);

    int n4 = T * D_DIM / 4;
    cast_x_kernel<<<(n4 + 255) / 256, 256, 0, stream>>>(x, xb, n4);
    gate_kernel<<<T / 4, 256, 0, stream>>>(x, gw, counts, perm, wts, islot, T);
    offsets_kernel<<<1, 64, 0, stream>>>(counts, offs);

    // expert in low 3 bits of grid.x -> XCD-aligned with the GEMMs
    dim3 gt13((F_DIM / 64) * N_EXP, D_DIM / 64);
    transpose_cast_kernel<<<gt13, 256, 0, stream>>>(w1, w1t, D_DIM, F_DIM);
    transpose_cast_kernel<<<gt13, 256, 0, stream>>>(w3, w3t, D_DIM, F_DIM);

    gemm1_kernel<<<(F_DIM / 128) * N_EXP * 16, 256, 0, stream>>>(
        xb, w1t, w3t, counts, offs, perm, hbuf, T);

    dim3 gt2((D_DIM / 64) * N_EXP, F_DIM / 64);
    transpose_cast_kernel<<<gt2, 256, 0, stream>>>(w2, w2t, F_DIM, D_DIM);

    gemm2_kernel<<<(D_DIM / 128) * N_EXP * 16, 256, 0, stream>>>(
        hbuf, w2t, counts, offs, wts, obuf, T);

    combine_kernel<<<(T * D_DIM / 4 + 255) / 256, 256, 0, stream>>>(obuf, islot, offs, out, T);
}